// Round 9
// baseline (1095.453 us; speedup 1.0000x reference)
//
#include <hip/hip_runtime.h>
#include <stdint.h>

// Problem constants (setup_inputs is fixed)
#define HH 192
#define WW 192
#define BB 8
#define NSTEP 10
#define HWSZ (HH*WW)    // 36864
#define NPIX (BB*HWSZ)  // 294912
#define TILE_W 24
#define TILE_H 16
#define XROWS 22        // TILE_H + 6 halo rows
#define XCOLS 30        // TILE_W + 6 halo cols
#define RSU   488       // ushorts per LDS row (16B-aligned, 2-way banks)
#define XBUFU (XROWS*RSU)   // 10736 ushorts per buffer (hi); lo at +XBUFU
#define NKS   25        // K-steps: 50 taps (49 + 1 zero-pad) * 16 ci / 32
#define NBLK  (8*12*8)  // conv1 grid = 768 blocks

typedef _Float16 f16x8 __attribute__((ext_vector_type(8)));
typedef float    f32x4 __attribute__((ext_vector_type(4)));

union PackU { ushort u[8]; uint4 v; };

// ---------------- Threefry-2x32 (exact JAX semantics) ----------------
__host__ __device__ inline void tf2x32(uint32_t k0, uint32_t k1,
                                       uint32_t x0, uint32_t x1,
                                       uint32_t &o0, uint32_t &o1) {
  const uint32_t k2 = k0 ^ k1 ^ 0x1BD11BDAu;
  x0 += k0; x1 += k1;
#define TFR(r) { x0 += x1; x1 = (x1 << (r)) | (x1 >> (32 - (r))); x1 ^= x0; }
  TFR(13) TFR(15) TFR(26) TFR(6)
  x0 += k1; x1 += k2 + 1u;
  TFR(17) TFR(29) TFR(16) TFR(24)
  x0 += k2; x1 += k0 + 2u;
  TFR(13) TFR(15) TFR(26) TFR(6)
  x0 += k0; x1 += k1 + 3u;
  TFR(17) TFR(29) TFR(16) TFR(24)
  x0 += k1; x1 += k2 + 4u;
  TFR(13) TFR(15) TFR(26) TFR(6)
  x0 += k2; x1 += k0 + 5u;
#undef TFR
  o0 = x0; o1 = x1;
}

__device__ inline void split2048(float v, ushort &h, ushort &l) {
  _Float16 hi = (_Float16)v;
  float r = (v - (float)hi) * 2048.0f;   // scale lo into normal f16 range
  _Float16 lo = (_Float16)r;
  h = __builtin_bit_cast(ushort, hi);
  l = __builtin_bit_cast(ushort, lo);
}

// ------------- K0a: weights -> A-fragment order, f16 hi/lo (lo scaled x2048) -------------
// frag f = (s*4 + mt)*64 + lane; lane: m = lane&15 -> j = mt*16+m; g = lane>>4;
// elems e: k = 32s + 8g + e -> tap t = 2s + (g>>1), ci = 8*(g&1) + e.
__global__ void k_prep_wfrag(const float* __restrict__ w1,
                             ushort* __restrict__ wfh, ushort* __restrict__ wfl) {
  int idx = blockIdx.x * 256 + threadIdx.x;   // 6400 total
  if (idx >= NKS * 4 * 64) return;
  const int lane = idx & 63;
  const int sm = idx >> 6;            // s*4 + mt
  const int s = sm >> 2, mt = sm & 3;
  const int m = lane & 15, g = lane >> 4;
  const int j = mt * 16 + m, co = j >> 2, r = j & 3;
  const int t = 2 * s + (g >> 1);
  PackU ph, pl;
#pragma unroll
  for (int e = 0; e < 8; ++e) {
    const int ci = 8 * (g & 1) + e;
    float wv = 0.f;
    if (t < 49) {
      const int ky = t / 7, kx = t - (t / 7) * 7;
      int a = ky, b = kx;
      for (int i = 0; i < r; ++i) { int na = b, nb = 6 - a; a = na; b = nb; }
      wv = w1[((co * 16 + ci) * 7 + a) * 7 + b];
    }
    split2048(wv, ph.u[e], pl.u[e]);
  }
  ((uint4*)wfh)[sm * 64 + lane] = ph.v;
  ((uint4*)wfl)[sm * 64 + lane] = pl.v;
}

// ------------- K0b: wsum[o][ci] = 0.25 * sum_t w2[o,ci,t] -------------
__global__ void k_prep_w2(const float* __restrict__ w2, float* __restrict__ wsum) {
  int idx = threadIdx.x;  // 256 = o*16 + ci
  float s = 0.f;
  for (int t = 0; t < 4; ++t) s += w2[idx * 4 + t];
  wsum[idx] = 0.25f * s;
}

// ------------- K1: 7x7 P4 lifting conv via split-f16 MFMA + BN block partials -------------
// 16x24 pixel tile, 8 waves; wave wid owns pixel-col strips {3w,3w+1,3w+2}.
// Barrier-free K-loop, A reg-dbuf from L2, B reg-dbuf from persistent x LDS.
// One fence per iter (after loads): {cluster(s), loads(s+2)} share a sched region
// so the compiler interleaves next-next loads into the MFMA stream. No setprio
// (lockstep waves: prio starves the load-issuing wave). accC ordered Ah*Bl x12
// then Al*Bh x12 (dependence distance 12 -> no back-to-back accumulator stalls).
__global__ __launch_bounds__(512, 2) void k_conv1(
    const float* __restrict__ xsrc,   // NHWC [B,H,W,16]
    const ushort* __restrict__ wfh,   // A-frags hi  [NKS*2048] f16
    const ushort* __restrict__ wfl,   // A-frags lo (x2048)
    const float* __restrict__ b1,     // [16]
    float* __restrict__ y,            // [NPIX][64]
    float* __restrict__ partials)     // [NBLK][32]
{
  __shared__ __align__(16) ushort xsm[2 * XBUFU];      // 42944 B
  __shared__ float red2[8][32];
  const int tid = threadIdx.x;
  const int lane = tid & 63, wid = tid >> 6;
  const int x0 = blockIdx.x * TILE_W, y0 = blockIdx.y * TILE_H;
  const int b = blockIdx.z;

  // ---- stage x tile (+halo) as split f16, pixel-major; 16B per thread-item ----
  for (int p = tid; p < XROWS * XCOLS * 2; p += 512) {
    const int half = p & 1, t2 = p >> 1;
    const int lr = t2 / XCOLS, lc = t2 - (t2 / XCOLS) * XCOLS;
    const int gy = y0 + lr - 3, gx = x0 + lc - 3;
    float4 v0, v1;
    if ((unsigned)gy < (unsigned)HH && (unsigned)gx < (unsigned)WW) {
      const float4* px = (const float4*)(xsrc + ((size_t)b * HWSZ + (size_t)gy * WW + gx) * 16 + half * 8);
      v0 = px[0]; v1 = px[1];
    } else {
      v0 = v1 = make_float4(0.f, 0.f, 0.f, 0.f);
    }
    const float xv[8] = {v0.x, v0.y, v0.z, v0.w, v1.x, v1.y, v1.z, v1.w};
    PackU h, l;
#pragma unroll
    for (int c = 0; c < 8; ++c) split2048(xv[c], h.u[c], l.u[c]);
    const int ub = lr * RSU + lc * 16 + half * 8;
    *(uint4*)&xsm[ub] = h.v;
    *(uint4*)&xsm[XBUFU + ub] = l.v;
  }
  __syncthreads();   // the ONLY barrier before epilogue: LDS read-only afterwards

  // ---- per-lane geometry ----
  const int n = lane & 15;            // D col = pixel row in tile
  const int q = lane >> 4;            // D row group
  const int h = q & 1;                // ci half for B reads
  const int bU0 = n * RSU + (3 * wid + 0) * 16 + h * 8;
  const int bU1 = bU0 + 16;
  const int bU2 = bU0 + 32;

  const f16x8* __restrict__ WAh = (const f16x8*)wfh;
  const f16x8* __restrict__ WAl = (const f16x8*)wfl;

  float bias[4];
#pragma unroll
  for (int mt = 0; mt < 4; ++mt) bias[mt] = b1[mt * 4 + q];

  f32x4 accH[3][4], accC[3][4];
#pragma unroll
  for (int st = 0; st < 3; ++st)
#pragma unroll
    for (int mt = 0; mt < 4; ++mt) {
      const float bv = bias[mt];
      accH[st][mt] = (f32x4){bv, bv, bv, bv};
      accC[st][mt] = (f32x4){0.f, 0.f, 0.f, 0.f};
    }

  f16x8 Ah[2][4], Al[2][4];
  f16x8 Bh[2][3], Bl[2][3];

  // prologue: step-0 fragments
#pragma unroll
  for (int mt = 0; mt < 4; ++mt) {
    Ah[0][mt] = WAh[mt * 64 + lane];
    Al[0][mt] = WAl[mt * 64 + lane];
  }
  {
    const int off = (lane < 32) ? 0 : 16;   // taps 0,1
    Bh[0][0] = *(const f16x8*)&xsm[bU0 + off];
    Bl[0][0] = *(const f16x8*)&xsm[XBUFU + bU0 + off];
    Bh[0][1] = *(const f16x8*)&xsm[bU1 + off];
    Bl[0][1] = *(const f16x8*)&xsm[XBUFU + bU1 + off];
    Bh[0][2] = *(const f16x8*)&xsm[bU2 + off];
    Bl[0][2] = *(const f16x8*)&xsm[XBUFU + bU2 + off];
  }

#pragma unroll
  for (int s = 0; s < NKS; ++s) {
    const int cb = s & 1, nb = cb ^ 1;
    if (s < NKS - 1) {
      // ---- prefetch step s+1: A from global (L2), B from LDS ----
#pragma unroll
      for (int mt = 0; mt < 4; ++mt) {
        const int f = ((s + 1) * 4 + mt) * 64 + lane;
        Ah[nb][mt] = WAh[f];
        Al[nb][mt] = WAl[f];
      }
      const int t0 = 2 * (s + 1), t1 = t0 + 1;
      const int o0 = (t0 / 7) * RSU + (t0 % 7) * 16;
      const int o1 = (t1 < 49) ? (t1 / 7) * RSU + (t1 % 7) * 16 : 0;  // pad tap: w=0
      const int off = (lane < 32) ? o0 : o1;
      Bh[nb][0] = *(const f16x8*)&xsm[bU0 + off];
      Bl[nb][0] = *(const f16x8*)&xsm[XBUFU + bU0 + off];
      Bh[nb][1] = *(const f16x8*)&xsm[bU1 + off];
      Bl[nb][1] = *(const f16x8*)&xsm[XBUFU + bU1 + off];
      Bh[nb][2] = *(const f16x8*)&xsm[bU2 + off];
      Bl[nb][2] = *(const f16x8*)&xsm[XBUFU + bU2 + off];
    }
    __builtin_amdgcn_sched_barrier(0);   // loads pinned above; cluster + next loads co-schedule below
    // 12 independent hh MFMAs
#pragma unroll
    for (int mt = 0; mt < 4; ++mt) {
#pragma unroll
      for (int st = 0; st < 3; ++st)
        accH[st][mt] = __builtin_amdgcn_mfma_f32_16x16x32_f16(Ah[cb][mt], Bh[cb][st], accH[st][mt], 0, 0, 0);
    }
    // 12 independent Ah*Bl, then 12 Al*Bh at dependence distance 12
#pragma unroll
    for (int mt = 0; mt < 4; ++mt) {
#pragma unroll
      for (int st = 0; st < 3; ++st)
        accC[st][mt] = __builtin_amdgcn_mfma_f32_16x16x32_f16(Ah[cb][mt], Bl[cb][st], accC[st][mt], 0, 0, 0);
    }
#pragma unroll
    for (int mt = 0; mt < 4; ++mt) {
#pragma unroll
      for (int st = 0; st < 3; ++st)
        accC[st][mt] = __builtin_amdgcn_mfma_f32_16x16x32_f16(Al[cb][mt], Bh[cb][st], accC[st][mt], 0, 0, 0);
    }
  }

  // ---- epilogue: combine, store y, BN partials ----
  float sC[4] = {0.f, 0.f, 0.f, 0.f}, qC[4] = {0.f, 0.f, 0.f, 0.f};
#pragma unroll
  for (int st = 0; st < 3; ++st) {
    const size_t pix = (size_t)b * HWSZ + (size_t)(y0 + n) * WW + (x0 + 3 * wid + st);
#pragma unroll
    for (int mt = 0; mt < 4; ++mt) {
      f32x4 res = accH[st][mt] + accC[st][mt] * 4.8828125e-4f;  // 1/2048
      *(float4*)(y + pix * 64 + mt * 16 + q * 4) =
          make_float4(res[0], res[1], res[2], res[3]);
#pragma unroll
      for (int r = 0; r < 4; ++r) { sC[mt] += res[r]; qC[mt] += res[r] * res[r]; }
    }
  }
#pragma unroll
  for (int mt = 0; mt < 4; ++mt) {
    float s = sC[mt], s2 = qC[mt];
#pragma unroll
    for (int off = 1; off <= 8; off <<= 1) {
      s += __shfl_xor(s, off); s2 += __shfl_xor(s2, off);
    }
    if (n == 0) {   // lane q*16: channel c = mt*4 + q
      red2[wid][(mt * 4 + q) * 2] = s;
      red2[wid][(mt * 4 + q) * 2 + 1] = s2;
    }
  }
  __syncthreads();
  if (tid < 32) {
    float v = 0.f;
#pragma unroll
    for (int w2i = 0; w2i < 8; ++w2i) v += red2[w2i][tid];
    const int blk = (b * gridDim.y + blockIdx.y) * gridDim.x + blockIdx.x;
    partials[(size_t)blk * 32 + tid] = v;
  }
}

// ------------- K2: reduce BN partials -> scale/shift per channel -------------
__global__ __launch_bounds__(256) void k_bnstats(
    const float* __restrict__ partials,  // [NBLK][32]
    const float* __restrict__ gamma, const float* __restrict__ beta,
    float* __restrict__ stats)           // [16][2] = scale, shift
{
  const int c = blockIdx.x;      // 16 blocks
  const int tid = threadIdx.x;   // 256
  float s = 0.f, s2 = 0.f;
  for (int i = tid; i < NBLK; i += 256) {
    s  += partials[(size_t)i * 32 + 2 * c];
    s2 += partials[(size_t)i * 32 + 2 * c + 1];
  }
  __shared__ float rs[256], rs2[256];
  rs[tid] = s; rs2[tid] = s2;
  __syncthreads();
  for (int off = 128; off > 0; off >>= 1) {
    if (tid < off) { rs[tid] += rs[tid + off]; rs2[tid] += rs2[tid + off]; }
    __syncthreads();
  }
  if (tid == 0) {
    const float N = (float)BB * 4.f * HH * WW;  // 1,179,648
    const float mu = rs[0] / N;
    const float var = rs2[0] / N - mu * mu;
    const float rstd = rsqrtf(var + 1e-5f);
    const float sc = gamma[c] * rstd;
    stats[2 * c]     = sc;
    stats[2 * c + 1] = beta[c] - mu * sc;
  }
}

// ------------- K3: BN+relu+orientation-sum+1x1 conv+mask+state update -------------
__global__ __launch_bounds__(256) void k_update(
    const float* __restrict__ xsrc,  // NHWC state (d_in step0, else d_out)
    const float* __restrict__ y,     // [NPIX][64]
    const float* __restrict__ stats, // [16][2]
    const float* __restrict__ wsum,  // [16][16]
    const float* __restrict__ b2,    // [16]
    float* __restrict__ xdst,        // NHWC state out (d_out)
    uint32_t fk0, uint32_t fk1)
{
  __shared__ float sss[32];
  __shared__ float sws[256];
  __shared__ float sb2[16];
  const int tid = threadIdx.x;
  sws[tid] = wsum[tid];
  if (tid < 32) sss[tid] = stats[tid];
  if (tid < 16) sb2[tid] = b2[tid];
  __syncthreads();

  const size_t pix = (size_t)blockIdx.x * 256 + tid;  // < NPIX exactly
  const float4* yp = (const float4*)(y + pix * 64);
  float ysum[16];
#pragma unroll
  for (int c = 0; c < 16; ++c) {
    const float4 v = yp[c];
    const float sc = sss[2 * c], sh = sss[2 * c + 1];
    ysum[c] = fmaxf(fmaf(sc, v.x, sh), 0.f) + fmaxf(fmaf(sc, v.y, sh), 0.f)
            + fmaxf(fmaf(sc, v.z, sh), 0.f) + fmaxf(fmaf(sc, v.w, sh), 0.f);
  }

  // JAX partitionable threefry: bits = h0 ^ h1 of hash(fk, (0, i))
  uint32_t h0, h1;
  tf2x32(fk0, fk1, 0u, (uint32_t)pix, h0, h1);
  const uint32_t bits = h0 ^ h1;
  const float u = __uint_as_float((bits >> 9) | 0x3f800000u) - 1.0f;
  const float m = (u > 0.5f) ? 1.0f : 0.0f;

  const float4* xp = (const float4*)(xsrc + pix * 16);
  float4* op = (float4*)(xdst + pix * 16);
#pragma unroll
  for (int qq = 0; qq < 4; ++qq) {
    const float4 xv = xp[qq];
    float d[4];
#pragma unroll
    for (int jj = 0; jj < 4; ++jj) {
      const int o = 4 * qq + jj;
      float s = sb2[o];
#pragma unroll
      for (int c = 0; c < 16; ++c) s = fmaf(sws[o * 16 + c], ysum[c], s);
      d[jj] = s;
    }
    float4 r;
    r.x = xv.x + d[0] * m;
    r.y = xv.y + d[1] * m;
    r.z = xv.z + d[2] * m;
    r.w = xv.w + d[3] * m;
    if (qq == 0) r.x = xv.x;  // channel 0 clamped to original input
    op[qq] = r;
  }
}

extern "C" void kernel_launch(void* const* d_in, const int* in_sizes, int n_in,
                              void* d_out, int out_size, void* d_ws, size_t ws_size,
                              hipStream_t stream) {
  const float* x_in  = (const float*)d_in[0];
  const float* w1    = (const float*)d_in[1];
  const float* b1    = (const float*)d_in[2];
  const float* gamma = (const float*)d_in[3];
  const float* beta  = (const float*)d_in[4];
  const float* w2    = (const float*)d_in[5];
  const float* b2    = (const float*)d_in[6];
  float* out = (float*)d_out;

  // workspace carve-up: y (75.5 MB) + wfrags + small buffers
  float* ws       = (float*)d_ws;
  float* y        = ws;                                // NPIX*64 floats
  ushort* wfh     = (ushort*)(y + (size_t)NPIX * 64);  // 25*2048 = 51200 ushorts
  ushort* wfl     = wfh + NKS * 2048;
  float* wsum     = (float*)(wfl + NKS * 2048);        // 16B aligned
  float* partials = wsum + 256;                        // NBLK*32
  float* stats    = partials + NBLK * 32;              // 32

  k_prep_wfrag<<<NKS, 256, 0, stream>>>(w1, wfh, wfl);
  k_prep_w2<<<1, 256, 0, stream>>>(w2, wsum);

  for (int s = 0; s < NSTEP; ++s) {
    const float* xsrc = (s == 0) ? x_in : out;
    k_conv1<<<dim3(WW / TILE_W, HH / TILE_H, BB), 512, 0, stream>>>(xsrc, wfh, wfl, b1, y, partials);
    k_bnstats<<<16, 256, 0, stream>>>(partials, gamma, beta, stats);
    uint32_t fk0, fk1;
    tf2x32(0u, 42u, 0u, (uint32_t)s, fk0, fk1);
    k_update<<<NPIX / 256, 256, 0, stream>>>(xsrc, y, stats, wsum, b2, out, fk0, fk1);
  }
}

// Round 10
// 1063.734 us; speedup vs baseline: 1.0298x; 1.0298x over previous
//
#include <hip/hip_runtime.h>
#include <stdint.h>

// Problem constants (setup_inputs is fixed)
#define HH 192
#define WW 192
#define BB 8
#define NSTEP 10
#define HWSZ (HH*WW)    // 36864
#define NPIX (BB*HWSZ)  // 294912
#define TILE_W 12
#define TILE_H 16
#define XROWS 22        // TILE_H + 6 halo rows
#define XCOLS 18        // TILE_W + 6 halo cols
#define RSU   296       // ushorts per LDS row (16B-aligned; dword stride 148 ≡ 20 mod 32)
#define XBUFU (XROWS*RSU)   // 6512 ushorts per buffer (hi); lo at +XBUFU
#define NKS   25        // K-steps: 50 taps (49 + 1 zero-pad) * 16 ci / 32
#define NBLK  (16*12*8) // conv1 grid = 1536 blocks

typedef _Float16 f16x8 __attribute__((ext_vector_type(8)));
typedef float    f32x4 __attribute__((ext_vector_type(4)));

union PackU { ushort u[8]; uint4 v; };

// ---------------- Threefry-2x32 (exact JAX semantics) ----------------
__host__ __device__ inline void tf2x32(uint32_t k0, uint32_t k1,
                                       uint32_t x0, uint32_t x1,
                                       uint32_t &o0, uint32_t &o1) {
  const uint32_t k2 = k0 ^ k1 ^ 0x1BD11BDAu;
  x0 += k0; x1 += k1;
#define TFR(r) { x0 += x1; x1 = (x1 << (r)) | (x1 >> (32 - (r))); x1 ^= x0; }
  TFR(13) TFR(15) TFR(26) TFR(6)
  x0 += k1; x1 += k2 + 1u;
  TFR(17) TFR(29) TFR(16) TFR(24)
  x0 += k2; x1 += k0 + 2u;
  TFR(13) TFR(15) TFR(26) TFR(6)
  x0 += k0; x1 += k1 + 3u;
  TFR(17) TFR(29) TFR(16) TFR(24)
  x0 += k1; x1 += k2 + 4u;
  TFR(13) TFR(15) TFR(26) TFR(6)
  x0 += k2; x1 += k0 + 5u;
#undef TFR
  o0 = x0; o1 = x1;
}

__device__ inline void split2048(float v, ushort &h, ushort &l) {
  _Float16 hi = (_Float16)v;
  float r = (v - (float)hi) * 2048.0f;   // scale lo into normal f16 range
  _Float16 lo = (_Float16)r;
  h = __builtin_bit_cast(ushort, hi);
  l = __builtin_bit_cast(ushort, lo);
}

// ------------- K0a: weights -> A-fragment order, f16 hi/lo (lo scaled x2048) -------------
// frag f = (s*4 + mt)*64 + lane; lane: m = lane&15 -> j = mt*16+m; g = lane>>4;
// elems e: k = 32s + 8g + e -> tap t = 2s + (g>>1), ci = 8*(g&1) + e.
__global__ void k_prep_wfrag(const float* __restrict__ w1,
                             ushort* __restrict__ wfh, ushort* __restrict__ wfl) {
  int idx = blockIdx.x * 256 + threadIdx.x;   // 6400 total
  if (idx >= NKS * 4 * 64) return;
  const int lane = idx & 63;
  const int sm = idx >> 6;            // s*4 + mt
  const int s = sm >> 2, mt = sm & 3;
  const int m = lane & 15, g = lane >> 4;
  const int j = mt * 16 + m, co = j >> 2, r = j & 3;
  const int t = 2 * s + (g >> 1);
  PackU ph, pl;
#pragma unroll
  for (int e = 0; e < 8; ++e) {
    const int ci = 8 * (g & 1) + e;
    float wv = 0.f;
    if (t < 49) {
      const int ky = t / 7, kx = t - (t / 7) * 7;
      int a = ky, b = kx;
      for (int i = 0; i < r; ++i) { int na = b, nb = 6 - a; a = na; b = nb; }
      wv = w1[((co * 16 + ci) * 7 + a) * 7 + b];
    }
    split2048(wv, ph.u[e], pl.u[e]);
  }
  ((uint4*)wfh)[sm * 64 + lane] = ph.v;
  ((uint4*)wfl)[sm * 64 + lane] = pl.v;
}

// ------------- K0b: wsum[o][ci] = 0.25 * sum_t w2[o,ci,t] -------------
__global__ void k_prep_w2(const float* __restrict__ w2, float* __restrict__ wsum) {
  int idx = threadIdx.x;  // 256 = o*16 + ci
  float s = 0.f;
  for (int t = 0; t < 4; ++t) s += w2[idx * 4 + t];
  wsum[idx] = 0.25f * s;
}

// ------------- K1: 7x7 P4 lifting conv via split-f16 MFMA + BN block partials -------------
// 16x12 pixel tile, 256 threads (4 waves); wave wid owns strips {3w,3w+1,3w+2}.
// Same per-wave K-loop as before, but 2 RESIDENT BLOCKS per CU: the 2 waves on
// each SIMD come from independent blocks with decorrelated phases, so one
// wave's load phase overlaps the other's MFMA cluster (m114 mechanism).
__global__ __launch_bounds__(256, 2) void k_conv1(
    const float* __restrict__ xsrc,   // NHWC [B,H,W,16]
    const ushort* __restrict__ wfh,   // A-frags hi  [NKS*2048] f16
    const ushort* __restrict__ wfl,   // A-frags lo (x2048)
    const float* __restrict__ b1,     // [16]
    float* __restrict__ y,            // [NPIX][64]
    float* __restrict__ partials)     // [NBLK][32]
{
  __shared__ __align__(16) ushort xsm[2 * XBUFU];      // 26048 B
  __shared__ float red2[4][32];
  const int tid = threadIdx.x;
  const int lane = tid & 63, wid = tid >> 6;
  const int x0 = blockIdx.x * TILE_W, y0 = blockIdx.y * TILE_H;
  const int b = blockIdx.z;

  // ---- stage x tile (+halo) as split f16, pixel-major; 16B per thread-item ----
  for (int p = tid; p < XROWS * XCOLS * 2; p += 256) {
    const int half = p & 1, t2 = p >> 1;
    const int lr = t2 / XCOLS, lc = t2 - (t2 / XCOLS) * XCOLS;
    const int gy = y0 + lr - 3, gx = x0 + lc - 3;
    float4 v0, v1;
    if ((unsigned)gy < (unsigned)HH && (unsigned)gx < (unsigned)WW) {
      const float4* px = (const float4*)(xsrc + ((size_t)b * HWSZ + (size_t)gy * WW + gx) * 16 + half * 8);
      v0 = px[0]; v1 = px[1];
    } else {
      v0 = v1 = make_float4(0.f, 0.f, 0.f, 0.f);
    }
    const float xv[8] = {v0.x, v0.y, v0.z, v0.w, v1.x, v1.y, v1.z, v1.w};
    PackU h, l;
#pragma unroll
    for (int c = 0; c < 8; ++c) split2048(xv[c], h.u[c], l.u[c]);
    const int ub = lr * RSU + lc * 16 + half * 8;
    *(uint4*)&xsm[ub] = h.v;
    *(uint4*)&xsm[XBUFU + ub] = l.v;
  }
  __syncthreads();   // the ONLY barrier before epilogue: LDS read-only afterwards

  // ---- per-lane geometry ----
  const int n = lane & 15;            // D col = pixel row in tile
  const int q = lane >> 4;            // D row group
  const int h = q & 1;                // ci half for B reads
  const int bU0 = n * RSU + (3 * wid + 0) * 16 + h * 8;
  const int bU1 = bU0 + 16;
  const int bU2 = bU0 + 32;

  const f16x8* __restrict__ WAh = (const f16x8*)wfh;
  const f16x8* __restrict__ WAl = (const f16x8*)wfl;

  float bias[4];
#pragma unroll
  for (int mt = 0; mt < 4; ++mt) bias[mt] = b1[mt * 4 + q];

  f32x4 accH[3][4], accC[3][4];
#pragma unroll
  for (int st = 0; st < 3; ++st)
#pragma unroll
    for (int mt = 0; mt < 4; ++mt) {
      const float bv = bias[mt];
      accH[st][mt] = (f32x4){bv, bv, bv, bv};
      accC[st][mt] = (f32x4){0.f, 0.f, 0.f, 0.f};
    }

  f16x8 Ah[2][4], Al[2][4];
  f16x8 Bh[2][3], Bl[2][3];

  // prologue: step-0 fragments
#pragma unroll
  for (int mt = 0; mt < 4; ++mt) {
    Ah[0][mt] = WAh[mt * 64 + lane];
    Al[0][mt] = WAl[mt * 64 + lane];
  }
  {
    const int off = (lane < 32) ? 0 : 16;   // taps 0,1
    Bh[0][0] = *(const f16x8*)&xsm[bU0 + off];
    Bl[0][0] = *(const f16x8*)&xsm[XBUFU + bU0 + off];
    Bh[0][1] = *(const f16x8*)&xsm[bU1 + off];
    Bl[0][1] = *(const f16x8*)&xsm[XBUFU + bU1 + off];
    Bh[0][2] = *(const f16x8*)&xsm[bU2 + off];
    Bl[0][2] = *(const f16x8*)&xsm[XBUFU + bU2 + off];
  }

#pragma unroll
  for (int s = 0; s < NKS; ++s) {
    const int cb = s & 1, nb = cb ^ 1;
    if (s < NKS - 1) {
      // ---- prefetch step s+1: A from global (L2), B from LDS ----
#pragma unroll
      for (int mt = 0; mt < 4; ++mt) {
        const int f = ((s + 1) * 4 + mt) * 64 + lane;
        Ah[nb][mt] = WAh[f];
        Al[nb][mt] = WAl[f];
      }
      const int t0 = 2 * (s + 1), t1 = t0 + 1;
      const int o0 = (t0 / 7) * RSU + (t0 % 7) * 16;
      const int o1 = (t1 < 49) ? (t1 / 7) * RSU + (t1 % 7) * 16 : 0;  // pad tap: w=0
      const int off = (lane < 32) ? o0 : o1;
      Bh[nb][0] = *(const f16x8*)&xsm[bU0 + off];
      Bl[nb][0] = *(const f16x8*)&xsm[XBUFU + bU0 + off];
      Bh[nb][1] = *(const f16x8*)&xsm[bU1 + off];
      Bl[nb][1] = *(const f16x8*)&xsm[XBUFU + bU1 + off];
      Bh[nb][2] = *(const f16x8*)&xsm[bU2 + off];
      Bl[nb][2] = *(const f16x8*)&xsm[XBUFU + bU2 + off];
    }
    __builtin_amdgcn_sched_barrier(0);   // loads pinned above the cluster
    __builtin_amdgcn_s_setprio(1);       // decorrelated co-resident waves: prio pays (T5 regime)
    // 12 independent hh MFMAs
#pragma unroll
    for (int mt = 0; mt < 4; ++mt) {
#pragma unroll
      for (int st = 0; st < 3; ++st)
        accH[st][mt] = __builtin_amdgcn_mfma_f32_16x16x32_f16(Ah[cb][mt], Bh[cb][st], accH[st][mt], 0, 0, 0);
    }
    // 12 independent Ah*Bl, then 12 Al*Bh at dependence distance 12
#pragma unroll
    for (int mt = 0; mt < 4; ++mt) {
#pragma unroll
      for (int st = 0; st < 3; ++st)
        accC[st][mt] = __builtin_amdgcn_mfma_f32_16x16x32_f16(Ah[cb][mt], Bl[cb][st], accC[st][mt], 0, 0, 0);
    }
#pragma unroll
    for (int mt = 0; mt < 4; ++mt) {
#pragma unroll
      for (int st = 0; st < 3; ++st)
        accC[st][mt] = __builtin_amdgcn_mfma_f32_16x16x32_f16(Al[cb][mt], Bh[cb][st], accC[st][mt], 0, 0, 0);
    }
    __builtin_amdgcn_s_setprio(0);
  }

  // ---- epilogue: combine, store y, BN partials ----
  float sC[4] = {0.f, 0.f, 0.f, 0.f}, qC[4] = {0.f, 0.f, 0.f, 0.f};
#pragma unroll
  for (int st = 0; st < 3; ++st) {
    const size_t pix = (size_t)b * HWSZ + (size_t)(y0 + n) * WW + (x0 + 3 * wid + st);
#pragma unroll
    for (int mt = 0; mt < 4; ++mt) {
      f32x4 res = accH[st][mt] + accC[st][mt] * 4.8828125e-4f;  // 1/2048
      *(float4*)(y + pix * 64 + mt * 16 + q * 4) =
          make_float4(res[0], res[1], res[2], res[3]);
#pragma unroll
      for (int r = 0; r < 4; ++r) { sC[mt] += res[r]; qC[mt] += res[r] * res[r]; }
    }
  }
#pragma unroll
  for (int mt = 0; mt < 4; ++mt) {
    float s = sC[mt], s2 = qC[mt];
#pragma unroll
    for (int off = 1; off <= 8; off <<= 1) {
      s += __shfl_xor(s, off); s2 += __shfl_xor(s2, off);
    }
    if (n == 0) {   // lane q*16: channel c = mt*4 + q
      red2[wid][(mt * 4 + q) * 2] = s;
      red2[wid][(mt * 4 + q) * 2 + 1] = s2;
    }
  }
  __syncthreads();
  if (tid < 32) {
    float v = red2[0][tid] + red2[1][tid] + red2[2][tid] + red2[3][tid];
    const int blk = (b * gridDim.y + blockIdx.y) * gridDim.x + blockIdx.x;
    partials[(size_t)blk * 32 + tid] = v;
  }
}

// ------------- K2: reduce BN partials -> scale/shift per channel -------------
__global__ __launch_bounds__(256) void k_bnstats(
    const float* __restrict__ partials,  // [NBLK][32]
    const float* __restrict__ gamma, const float* __restrict__ beta,
    float* __restrict__ stats)           // [16][2] = scale, shift
{
  const int c = blockIdx.x;      // 16 blocks
  const int tid = threadIdx.x;   // 256
  float s = 0.f, s2 = 0.f;
  for (int i = tid; i < NBLK; i += 256) {
    s  += partials[(size_t)i * 32 + 2 * c];
    s2 += partials[(size_t)i * 32 + 2 * c + 1];
  }
  __shared__ float rs[256], rs2[256];
  rs[tid] = s; rs2[tid] = s2;
  __syncthreads();
  for (int off = 128; off > 0; off >>= 1) {
    if (tid < off) { rs[tid] += rs[tid + off]; rs2[tid] += rs2[tid + off]; }
    __syncthreads();
  }
  if (tid == 0) {
    const float N = (float)BB * 4.f * HH * WW;  // 1,179,648
    const float mu = rs[0] / N;
    const float var = rs2[0] / N - mu * mu;
    const float rstd = rsqrtf(var + 1e-5f);
    const float sc = gamma[c] * rstd;
    stats[2 * c]     = sc;
    stats[2 * c + 1] = beta[c] - mu * sc;
  }
}

// ------------- K3: BN+relu+orientation-sum+1x1 conv+mask+state update -------------
__global__ __launch_bounds__(256) void k_update(
    const float* __restrict__ xsrc,  // NHWC state (d_in step0, else d_out)
    const float* __restrict__ y,     // [NPIX][64]
    const float* __restrict__ stats, // [16][2]
    const float* __restrict__ wsum,  // [16][16]
    const float* __restrict__ b2,    // [16]
    float* __restrict__ xdst,        // NHWC state out (d_out)
    uint32_t fk0, uint32_t fk1)
{
  __shared__ float sss[32];
  __shared__ float sws[256];
  __shared__ float sb2[16];
  const int tid = threadIdx.x;
  sws[tid] = wsum[tid];
  if (tid < 32) sss[tid] = stats[tid];
  if (tid < 16) sb2[tid] = b2[tid];
  __syncthreads();

  const size_t pix = (size_t)blockIdx.x * 256 + tid;  // < NPIX exactly
  const float4* yp = (const float4*)(y + pix * 64);
  float ysum[16];
#pragma unroll
  for (int c = 0; c < 16; ++c) {
    const float4 v = yp[c];
    const float sc = sss[2 * c], sh = sss[2 * c + 1];
    ysum[c] = fmaxf(fmaf(sc, v.x, sh), 0.f) + fmaxf(fmaf(sc, v.y, sh), 0.f)
            + fmaxf(fmaf(sc, v.z, sh), 0.f) + fmaxf(fmaf(sc, v.w, sh), 0.f);
  }

  // JAX partitionable threefry: bits = h0 ^ h1 of hash(fk, (0, i))
  uint32_t h0, h1;
  tf2x32(fk0, fk1, 0u, (uint32_t)pix, h0, h1);
  const uint32_t bits = h0 ^ h1;
  const float u = __uint_as_float((bits >> 9) | 0x3f800000u) - 1.0f;
  const float m = (u > 0.5f) ? 1.0f : 0.0f;

  const float4* xp = (const float4*)(xsrc + pix * 16);
  float4* op = (float4*)(xdst + pix * 16);
#pragma unroll
  for (int qq = 0; qq < 4; ++qq) {
    const float4 xv = xp[qq];
    float d[4];
#pragma unroll
    for (int jj = 0; jj < 4; ++jj) {
      const int o = 4 * qq + jj;
      float s = sb2[o];
#pragma unroll
      for (int c = 0; c < 16; ++c) s = fmaf(sws[o * 16 + c], ysum[c], s);
      d[jj] = s;
    }
    float4 r;
    r.x = xv.x + d[0] * m;
    r.y = xv.y + d[1] * m;
    r.z = xv.z + d[2] * m;
    r.w = xv.w + d[3] * m;
    if (qq == 0) r.x = xv.x;  // channel 0 clamped to original input
    op[qq] = r;
  }
}

extern "C" void kernel_launch(void* const* d_in, const int* in_sizes, int n_in,
                              void* d_out, int out_size, void* d_ws, size_t ws_size,
                              hipStream_t stream) {
  const float* x_in  = (const float*)d_in[0];
  const float* w1    = (const float*)d_in[1];
  const float* b1    = (const float*)d_in[2];
  const float* gamma = (const float*)d_in[3];
  const float* beta  = (const float*)d_in[4];
  const float* w2    = (const float*)d_in[5];
  const float* b2    = (const float*)d_in[6];
  float* out = (float*)d_out;

  // workspace carve-up: y (75.5 MB) + wfrags + small buffers
  float* ws       = (float*)d_ws;
  float* y        = ws;                                // NPIX*64 floats
  ushort* wfh     = (ushort*)(y + (size_t)NPIX * 64);  // 25*2048 = 51200 ushorts
  ushort* wfl     = wfh + NKS * 2048;
  float* wsum     = (float*)(wfl + NKS * 2048);        // 16B aligned
  float* partials = wsum + 256;                        // NBLK*32
  float* stats    = partials + NBLK * 32;              // 32

  k_prep_wfrag<<<NKS, 256, 0, stream>>>(w1, wfh, wfl);
  k_prep_w2<<<1, 256, 0, stream>>>(w2, wsum);

  for (int s = 0; s < NSTEP; ++s) {
    const float* xsrc = (s == 0) ? x_in : out;
    k_conv1<<<dim3(WW / TILE_W, HH / TILE_H, BB), 256, 0, stream>>>(xsrc, wfh, wfl, b1, y, partials);
    k_bnstats<<<16, 256, 0, stream>>>(partials, gamma, beta, stats);
    uint32_t fk0, fk1;
    tf2x32(0u, 42u, 0u, (uint32_t)s, fk0, fk1);
    k_update<<<NPIX / 256, 256, 0, stream>>>(xsrc, y, stats, wsum, b2, out, fk0, fk1);
  }
}